// Round 5
// baseline (1477.583 us; speedup 1.0000x reference)
//
#include <hip/hip_runtime.h>
#include <stdint.h>

#define H_    2048
#define B_    128
#define T_    64
#define E_    300
#define NKUX  10        // K units for hoisted x-GEMM (320 >= 300)
#define XGRP  48        // 384/8 x-groups per timestep
#define NWG   256
#define NTHR  512
#define NJG   128       // j-groups of 16 hidden cols
#define HBUF  (262144)  // one h buffer: 64ku * 4q * 128m * 8 bytes (i8)

#define WSCL  (0.14f / 127.f)            // int8 weight grid step
#define GSCL  (0.14f / (127.f * 127.f))  // gate unscale: Dw * Dh

typedef unsigned short u16;
typedef unsigned char u8;
typedef signed char s8;
typedef uint32_t u32;
typedef short bf8 __attribute__((ext_vector_type(8)));
typedef float f4 __attribute__((ext_vector_type(4)));
typedef int   i4 __attribute__((ext_vector_type(4)));
typedef long i64v;      // 8 packed i8 elems (2 VGPRs) per MFMA operand
typedef _Float16 f16;

__device__ __forceinline__ u16 f2b(float f) {
    u32 u = __float_as_uint(f);
    u += 0x7fffu + ((u >> 16) & 1u);   // round-to-nearest-even
    return (u16)(u >> 16);
}
__device__ __forceinline__ u16 f2h(float f) { f16 h = (f16)f; u16 u; __builtin_memcpy(&u, &h, 2); return u; }
__device__ __forceinline__ float h2f(u16 u) { f16 h; __builtin_memcpy(&h, &u, 2); return (float)h; }
__device__ __forceinline__ float sigm(float x) { return 1.f / (1.f + __expf(-x)); }
__device__ __forceinline__ float tanh_(float x) {
    float xx = fminf(fmaxf(x, -15.f), 15.f);
    float e = __expf(2.f * xx);
    return (e - 1.f) / (e + 1.f);
}
__device__ __forceinline__ s8 f2i8w(float f) {
    float v = f * (1.f / WSCL);
    v = fminf(fmaxf(v, -127.f), 127.f);
    return (s8)__float2int_rn(v);
}
__device__ __forceinline__ s8 f2i8h(float f) {
    float v = fminf(fmaxf(f * 127.f, -127.f), 127.f);
    return (s8)__float2int_rn(v);
}

// ---- prep: pack hh-weights int8 fragments, ih-weights bf16 fragments, biases, state ----
__global__ void prep_kernel(const float* __restrict__ w_hh, const float* __restrict__ w_ih,
                            const float* __restrict__ b_ih, const float* __restrict__ b_hh,
                            s8* __restrict__ wP8, u16* __restrict__ wiP,
                            float* __restrict__ bsP,
                            float* __restrict__ cP, s8* __restrict__ hR,
                            int* __restrict__ bar) {
    int tid = blockIdx.x * blockDim.x + threadIdx.x;
    int np = gridDim.x * blockDim.x;
    const int NF = NJG * 64 * 4 * 64;   // i8 hh fragments
    for (int f = tid; f < NF; f += np) {
        int lane = f & 63;
        int fr = f >> 6;
        int nt = fr & 3;
        int rest = fr >> 2;
        int ku = rest & 63;
        int jg = rest >> 6;
        int l15 = lane & 15, q = lane >> 4;
        int nl = nt * 16 + l15;
        int g = nl & 3, jj = nl >> 2;
        int ng = g * H_ + jg * 16 + jj;
        int k0 = ku * 32 + q * 8;
        union { s8 s[8]; uint2 v; } tmp;
#pragma unroll
        for (int j = 0; j < 8; ++j)
            tmp.s[j] = f2i8w(w_hh[(size_t)ng * H_ + k0 + j]);
        *(uint2*)&wP8[(size_t)f * 8] = tmp.v;
    }
    const int NFI = NJG * NKUX * 4 * 64;
    for (int f = tid; f < NFI; f += np) {
        int lane = f & 63;
        int fr = f >> 6;
        int nt = fr & 3;
        int rest = fr >> 2;
        int ku = rest % NKUX;
        int jg = rest / NKUX;
        int l15 = lane & 15, q = lane >> 4;
        int nl = nt * 16 + l15;
        int g = nl & 3, jj = nl >> 2;
        int ng = g * H_ + jg * 16 + jj;
        int k0 = ku * 32 + q * 8;
        union { u16 s[8]; uint4 v; } tmp;
#pragma unroll
        for (int j = 0; j < 8; ++j) {
            int k = k0 + j;
            tmp.s[j] = (k < E_) ? f2b(w_ih[(size_t)ng * E_ + k]) : (u16)0;
        }
        *(uint4*)&wiP[(size_t)f * 8] = tmp.v;
    }
    for (int n = tid; n < NJG * 64; n += np) {
        int jg = n >> 6, r = n & 63;
        int jj = r >> 2, g = r & 3;
        int src = g * H_ + jg * 16 + jj;
        bsP[n] = b_ih[src] + b_hh[src];
    }
    for (int i = tid; i < NJG * B_ * 16; i += np) cP[i] = 0.f;       // fallback c
    for (int i = tid; i < HBUF / 4; i += np) ((u32*)hR)[i] = 0u;     // h buffer 0
    for (int i = tid; i < 4096; i += np) bar[i] = 0;                 // barrier state
}

// ---- embedding gather -> packed bf16 xP[t][gx][b][8] ----
__global__ void gather_kernel(const int* __restrict__ input, const float* __restrict__ embed,
                              u16* __restrict__ xP) {
    int t = blockIdx.x;
    u16* xt = xP + (size_t)t * XGRP * B_ * 8;
    for (int id = threadIdx.x; id < XGRP * B_; id += blockDim.x) {
        int b = id & (B_ - 1);
        int gx = id >> 7;
        int row = input[b * T_ + t];
        const float* src = embed + (size_t)row * E_;
        union { u16 s[8]; uint4 v; } tmp;
#pragma unroll
        for (int j = 0; j < 8; ++j) {
            int k = gx * 8 + j;
            tmp.s[j] = (k < E_) ? f2b(src[k]) : (u16)0;
        }
        *(uint4*)&xt[(size_t)id * 8] = tmp.v;
    }
}

// ---- hoisted x-GEMM (bf16): xg[t][jg][m][jj*4+g] = x@W_ih^T + b_ih + b_hh, f16 out ----
__global__ __launch_bounds__(NTHR) void
xw_kernel(const u16* __restrict__ wiP, const u16* __restrict__ xP,
          const float* __restrict__ bsP, u16* __restrict__ xg) {
    int tid = threadIdx.x;
    int wid = tid >> 6, lane = tid & 63;
    int l15 = lane & 15, q = lane >> 4;
    int t  = blockIdx.x >> 7;
    int jg = blockIdx.x & 127;

    const u16* wbase = wiP + (size_t)jg * NKUX * 2048 + lane * 8;
    const u16* xbase = xP + (size_t)t * (XGRP * B_ * 8) + (size_t)(q * 128 + wid * 16 + l15) * 8;

    f4 acc[4];
#pragma unroll
    for (int nt = 0; nt < 4; ++nt) acc[nt] = (f4)0.f;

#pragma unroll
    for (int ku = 0; ku < NKUX; ++ku) {
        bf8 wf[4], xf;
        const u16* wb = wbase + (size_t)ku * 2048;
        wf[0] = *(const bf8*)(wb);
        wf[1] = *(const bf8*)(wb + 512);
        wf[2] = *(const bf8*)(wb + 1024);
        wf[3] = *(const bf8*)(wb + 1536);
        xf = *(const bf8*)(xbase + (size_t)ku * 4096);
#pragma unroll
        for (int nt = 0; nt < 4; ++nt)
            acc[nt] = __builtin_amdgcn_mfma_f32_16x16x32_bf16(wf[nt], xf, acc[nt], 0, 0, 0);
    }

    int m = wid * 16 + l15;
    u16* outb = xg + (((size_t)t * NJG + jg) * B_ + m) * 64;
#pragma unroll
    for (int nt = 0; nt < 4; ++nt) {
        f4 bv = *(const f4*)&bsP[jg * 64 + nt * 16 + q * 4];
        union { u16 s[4]; uint2 v; } hv;
        hv.s[0] = f2h(acc[nt][0] + bv[0]);
        hv.s[1] = f2h(acc[nt][1] + bv[1]);
        hv.s[2] = f2h(acc[nt][2] + bv[2]);
        hv.s[3] = f2h(acc[nt][3] + bv[3]);
        *(uint2*)&outb[nt * 16 + q * 4] = hv.v;
    }
}

#define LDF8(KU, WF, HB) do {                                                 \
        int ku_ = (KU);                                                       \
        const s8* wb_ = wbase + (size_t)ku_ * 2048;                           \
        WF[0] = *(const i64v*)(wb_);                                          \
        WF[1] = *(const i64v*)(wb_ + 512);                                    \
        WF[2] = *(const i64v*)(wb_ + 1024);                                   \
        WF[3] = *(const i64v*)(wb_ + 1536);                                   \
        const s8* hb_ = hin + (size_t)ku_ * 4096 + hoff;                      \
        HB[0] = *(const i64v*)(hb_);                                          \
        HB[1] = *(const i64v*)(hb_ + 128);                                    \
        HB[2] = *(const i64v*)(hb_ + 256);                                    \
        HB[3] = *(const i64v*)(hb_ + 384);                                    \
    } while (0)

#define MM8(WF, HB) do {                                                      \
        _Pragma("unroll")                                                     \
        for (int nt_ = 0; nt_ < 4; ++nt_)                                     \
            _Pragma("unroll")                                                 \
            for (int mt_ = 0; mt_ < 4; ++mt_)                                 \
                acc[nt_][mt_] = __builtin_amdgcn_mfma_i32_16x16x32_i8(        \
                    WF[nt_], HB[mt_], acc[nt_][mt_], 0, 0, 0);                \
    } while (0)

// ---- persistent cooperative kernel: all 64 steps, grid barrier between steps ----
// 256 WGs x 512 thr, 1/CU. WG owns (jg, wgm) for all t. h rotates through 65
// fresh buffers (no stale-line hazard). c lives in registers. Weights stay in L2.
__global__ __launch_bounds__(NTHR) void
loop_kernel(const s8* __restrict__ wP8, const u16* __restrict__ xgt,
            s8* __restrict__ hR, float* __restrict__ outp, int* __restrict__ bar) {
    __shared__ int bufs[8][16][68];
    int tid = threadIdx.x;
    int bid = blockIdx.x;
    int wid = tid >> 6, lane = tid & 63;
    int l15 = lane & 15, q = lane >> 4;
    int jg  = bid & 127;
    int wgm = bid >> 7;
    int jj = tid & 15, ml16 = (tid >> 4) & 15;

    const s8* wbase = wP8 + (size_t)jg * 64 * 2048 + lane * 8;
    int hoff = q * 1024 + wgm * 512 + l15 * 8;
    int ks = wid * 8;

    float creg[4] = {0.f, 0.f, 0.f, 0.f};   // c-state in registers (tid<256 uses it)

    for (int t = 0; t < T_; ++t) {
        const s8* hin = hR + (size_t)t * HBUF;
        s8* hout      = hR + (size_t)(t + 1) * HBUF;

        i4 acc[4][4];
#pragma unroll
        for (int nt = 0; nt < 4; ++nt)
#pragma unroll
            for (int mt = 0; mt < 4; ++mt) acc[nt][mt] = (i4)0;

        {
            i64v wB_[4][4], hB_[4][4];
#pragma unroll
            for (int i = 0; i < 3; ++i) LDF8(ks + i, wB_[i], hB_[i]);
#pragma unroll
            for (int i = 0; i < 8; ++i) {
                if (i + 3 < 8) LDF8(ks + i + 3, wB_[(i + 3) & 3], hB_[(i + 3) & 3]);
                MM8(wB_[i & 3], hB_[i & 3]);
            }
        }

        // epilogue: 4 m-phases of LDS reduce + cell
#pragma unroll
        for (int p = 0; p < 4; ++p) {
            __syncthreads();
            *(i4*)&bufs[wid][l15][0 * 16 + q * 4] = acc[0][p];
            *(i4*)&bufs[wid][l15][1 * 16 + q * 4] = acc[1][p];
            *(i4*)&bufs[wid][l15][2 * 16 + q * 4] = acc[2][p];
            *(i4*)&bufs[wid][l15][3 * 16 + q * 4] = acc[3][p];
            __syncthreads();
            if (tid < 256) {
                int m = wgm * 64 + p * 16 + ml16;
                i4 r = (i4)0;
#pragma unroll
                for (int w = 0; w < 8; ++w) {
                    i4 v = *(const i4*)&bufs[w][ml16][jj * 4];
                    r[0] += v[0]; r[1] += v[1]; r[2] += v[2]; r[3] += v[3];
                }
                union { uint2 v; u16 s[4]; } xu;
                xu.v = *(const uint2*)&xgt[(((size_t)t * NJG + jg) * B_ + m) * 64 + jj * 4];
                float s0 = h2f(xu.s[0]) + (float)r[0] * GSCL;
                float s1 = h2f(xu.s[1]) + (float)r[1] * GSCL;
                float s2 = h2f(xu.s[2]) + (float)r[2] * GSCL;
                float s3 = h2f(xu.s[3]) + (float)r[3] * GSCL;
                float iv = sigm(s0);
                float fv = sigm(s1);
                float gv = tanh_(s2);
                float ov = sigm(s3);
                float cn = fv * creg[p] + iv * gv;
                creg[p] = cn;
                float hn = ov * tanh_(cn);
                int jglob = jg * 16 + jj;
                hout[(size_t)(jglob >> 3) * 1024 + m * 8 + (jglob & 7)] = f2i8h(hn);
                if (t == T_ - 1) outp[(size_t)m * H_ + jglob] = hn;
            }
        }

        // grid barrier (skip after last step)
        if (t < T_ - 1) {
            __syncthreads();                  // all WG stores issued+drained
            if (tid == 0) {
                __threadfence();              // h writes to coherence point
                int old = __hip_atomic_fetch_add(&bar[(bid & 31) * 32], 1,
                                                 __ATOMIC_ACQ_REL, __HIP_MEMORY_SCOPE_AGENT);
                if (old == 7) {               // last of 8 in this leaf
                    int r = __hip_atomic_fetch_add(&bar[32 * 32], 1,
                                                   __ATOMIC_ACQ_REL, __HIP_MEMORY_SCOPE_AGENT);
                    if (r == 31) {            // last leaf: reset, then release flag
#pragma unroll
                        for (int l = 0; l < 32; ++l)
                            __hip_atomic_store(&bar[l * 32], 0,
                                               __ATOMIC_RELAXED, __HIP_MEMORY_SCOPE_AGENT);
                        __hip_atomic_store(&bar[32 * 32], 0,
                                           __ATOMIC_RELAXED, __HIP_MEMORY_SCOPE_AGENT);
                        __hip_atomic_store(&bar[33 * 32], t + 1,
                                           __ATOMIC_RELEASE, __HIP_MEMORY_SCOPE_AGENT);
                    }
                }
                while (__hip_atomic_load(&bar[33 * 32],
                                         __ATOMIC_RELAXED, __HIP_MEMORY_SCOPE_AGENT) < t + 1)
                    __builtin_amdgcn_s_sleep(2);
            }
            __syncthreads();
            asm volatile("" ::: "memory");
        }
    }
}

// ---- fallback multi-launch step (used only if cooperative launch fails) ----
__global__ __launch_bounds__(NTHR) void
step_kernel(const s8* __restrict__ wP8, const u16* __restrict__ xgt,
            const s8* __restrict__ hin,
            s8* __restrict__ hout, float* __restrict__ cP,
            float* __restrict__ outp) {
    __shared__ int bufs[8][16][68];
    int tid = threadIdx.x;
    int wid = tid >> 6, lane = tid & 63;
    int l15 = lane & 15, q = lane >> 4;
    int jg  = blockIdx.x & 127;
    int wgm = blockIdx.x >> 7;

    const s8* wbase = wP8 + (size_t)jg * 64 * 2048 + lane * 8;
    int hoff = q * 1024 + wgm * 512 + l15 * 8;

    i4 acc[4][4];
#pragma unroll
    for (int nt = 0; nt < 4; ++nt)
#pragma unroll
        for (int mt = 0; mt < 4; ++mt) acc[nt][mt] = (i4)0;

    {
        int ks = wid * 8;
        i64v wB_[4][4], hB_[4][4];
#pragma unroll
        for (int i = 0; i < 3; ++i) LDF8(ks + i, wB_[i], hB_[i]);
#pragma unroll
        for (int i = 0; i < 8; ++i) {
            if (i + 3 < 8) LDF8(ks + i + 3, wB_[(i + 3) & 3], hB_[(i + 3) & 3]);
            MM8(wB_[i & 3], hB_[i & 3]);
        }
    }

    int jj = tid & 15, ml16 = (tid >> 4) & 15;
#pragma unroll
    for (int p = 0; p < 4; ++p) {
        __syncthreads();
        *(i4*)&bufs[wid][l15][0 * 16 + q * 4] = acc[0][p];
        *(i4*)&bufs[wid][l15][1 * 16 + q * 4] = acc[1][p];
        *(i4*)&bufs[wid][l15][2 * 16 + q * 4] = acc[2][p];
        *(i4*)&bufs[wid][l15][3 * 16 + q * 4] = acc[3][p];
        __syncthreads();
        if (tid < 256) {
            int m = wgm * 64 + p * 16 + ml16;
            i4 r = (i4)0;
#pragma unroll
            for (int w = 0; w < 8; ++w) {
                i4 v = *(const i4*)&bufs[w][ml16][jj * 4];
                r[0] += v[0]; r[1] += v[1]; r[2] += v[2]; r[3] += v[3];
            }
            union { uint2 v; u16 s[4]; } xu;
            xu.v = *(const uint2*)&xgt[((size_t)jg * B_ + m) * 64 + jj * 4];
            float s0 = h2f(xu.s[0]) + (float)r[0] * GSCL;
            float s1 = h2f(xu.s[1]) + (float)r[1] * GSCL;
            float s2 = h2f(xu.s[2]) + (float)r[2] * GSCL;
            float s3 = h2f(xu.s[3]) + (float)r[3] * GSCL;
            float iv = sigm(s0);
            float fv = sigm(s1);
            float gv = tanh_(s2);
            float ov = sigm(s3);
            size_t ci = ((size_t)jg * B_ + m) * 16 + jj;
            float cn = fv * cP[ci] + iv * gv;
            cP[ci] = cn;
            float hn = ov * tanh_(cn);
            int jglob = jg * 16 + jj;
            hout[(size_t)(jglob >> 3) * 1024 + m * 8 + (jglob & 7)] = f2i8h(hn);
            if (outp) outp[(size_t)m * H_ + jglob] = hn;
        }
    }
}

#undef LDF8
#undef MM8

extern "C" void kernel_launch(void* const* d_in, const int* in_sizes, int n_in,
                              void* d_out, int out_size, void* d_ws, size_t ws_size,
                              hipStream_t stream) {
    const int*   input = (const int*)d_in[0];
    const float* embed = (const float*)d_in[1];
    const float* w_ih  = (const float*)d_in[2];
    const float* w_hh  = (const float*)d_in[3];
    const float* b_ih  = (const float*)d_in[4];
    const float* b_hh  = (const float*)d_in[5];
    float* out = (float*)d_out;

    char* ws = (char*)d_ws;
    size_t o = 0;
    s8*  wP8  = (s8*)(ws + o);  o += (size_t)NJG * 64 * 4 * 64 * 8;        // 16.8 MB i8 hh
    u16* wiP  = (u16*)(ws + o); o += (size_t)NJG * NKUX * 4 * 64 * 8 * 2;  // 5.24 MB
    u16* xP   = (u16*)(ws + o); o += (size_t)T_ * XGRP * B_ * 8 * 2;       // 6.29 MB
    s8*  hR   = (s8*)(ws + o);  o += (size_t)(T_ + 1) * HBUF;              // 17.0 MB rotating h
    float* cP = (float*)(ws + o); o += (size_t)NJG * B_ * 16 * 4;          // 1 MB (fallback)
    float* bsP = (float*)(ws + o); o += (size_t)4 * H_ * 4;                // 32 KB
    int* bar  = (int*)(ws + o); o += 4096 * 4;                             // 16 KB barrier
    u16* xgH  = (u16*)(ws + o); o += (size_t)T_ * NJG * B_ * 64 * 2;       // 134 MB f16 xg
    (void)ws_size;   // total ~181 MB; ws is 480 MB (poison fills)

    prep_kernel<<<2048, 256, 0, stream>>>(w_hh, w_ih, b_ih, b_hh, wP8, wiP, bsP, cP, hR, bar);
    gather_kernel<<<T_, 256, 0, stream>>>(input, embed, xP);
    xw_kernel<<<T_ * NJG, NTHR, 0, stream>>>(wiP, xP, bsP, xgH);

    const s8* a0 = wP8; const u16* a1 = xgH; s8* a2 = hR; float* a3 = out; int* a4 = bar;
    void* kargs[] = {(void*)&a0, (void*)&a1, (void*)&a2, (void*)&a3, (void*)&a4};
    hipError_t ce = hipLaunchCooperativeKernel((const void*)loop_kernel,
                                               dim3(NWG), dim3(NTHR), kargs, 0, stream);
    if (ce != hipSuccess) {
        (void)hipGetLastError();   // clear sticky error, use multi-launch path
        for (int t = 0; t < T_; ++t) {
            const s8* hin = hR + (size_t)t * HBUF;
            s8* hout      = hR + (size_t)(t + 1) * HBUF;
            float* hof    = (t == T_ - 1) ? out : nullptr;
            step_kernel<<<NWG, NTHR, 0, stream>>>(
                wP8, xgH + (size_t)t * NJG * B_ * 64, hin, hout, cP, hof);
        }
    }
}